// Round 13
// baseline (510.499 us; speedup 1.0000x reference)
//
#include <hip/hip_runtime.h>
#include <hip/hip_bf16.h>
#include <cstdint>

typedef __attribute__((ext_vector_type(8))) short short8;
typedef __attribute__((ext_vector_type(4))) float f32x4;
typedef unsigned short u16;

__device__ __forceinline__ float b2f(u16 u) {
  union { unsigned int i; float f; } v; v.i = ((unsigned int)u) << 16; return v.f;
}
// hardware RNE f32->bf16
__device__ __forceinline__ u16 f2b(float f) {
  __hip_bfloat16 h = __float2bfloat16(f);
  union { __hip_bfloat16 h; u16 u; } v; v.h = h; return v.u;
}
// silu via v_rcp_f32 (<=1ulp) instead of full-precision divide (~12 inst).
__device__ __forceinline__ float silu_f(float x) {
  return x * __builtin_amdgcn_rcpf(1.0f + __expf(-x));
}

__device__ __forceinline__ float loadF(const void* p, long i, int isf32) {
  if (isf32) return ((const float*)p)[i];
  return b2f(((const u16*)p)[i]);
}

// dtype sniff bit: f32 data viewed as u16 -> low halves are ~uniform-random;
// ~50% land outside bf16-exponent [2^-63, 2^65). Genuine bf16 N(0,1)/uniform
// data: none (zeros excluded).
__device__ __forceinline__ int sniffbit(u16 u) {
  unsigned e = (u >> 7) & 0xffu;
  return (e >= 0xC0u || (e < 0x40u && (u & 0x7fffu) != 0)) ? 1 : 0;
}

struct Ptrs { const void* p[20]; int n[20]; };

// f32 prepped-weight layout (float offsets)
#define FW_EW1 0
#define FW_UW1 384
#define FW_UW2 4480
#define FW_UB1 8576
#define FW_UB2 8640
#define FW_EB1 8704
#define FW_EB2 8768
#define FW_MB1 8832
#define FW_MB2 8896
#define FW_TOTAL 8960

// bf16 transposed image layout (u16 offsets)
#define IMG_EW2 0
#define IMG_MW1 4608
#define IMG_MW2 13312
#define IMG_TOTAL 17920

#define PREP_BLOCKS 105   // ceil((IMG_TOTAL + FW_TOTAL)/256)
#define HIST_BLOCKS 1024

// ---------------------------------------------------------------------------
// Kernel 1: dtype detection ONLY (tiny, ~3us). Lets K2 run hist CONCURRENTLY
// with prep + node-MLP (which need flags, not the histogram).
// ---------------------------------------------------------------------------
__global__ __launch_bounds__(256) void detect_k(Ptrs a, int* __restrict__ flags)
{
  const int t = threadIdx.x;
  const int j = blockIdx.x;
  const u16* q = (const u16*)a.p[j];
  int n = a.n[j];
  int m = n < 4096 ? n : 4096;
  int cnt = 0;
  for (int i = t; i < m; i += 256) cnt += sniffbit(q[i]);
  __shared__ int tot;
  if (t == 0) tot = 0;
  __syncthreads();
  if (cnt) atomicAdd(&tot, cnt);
  __syncthreads();
  if (t == 0) flags[j] = (tot >= 2) ? 1 : 0;
}

// ---------------------------------------------------------------------------
// Kernel 2: FUSED hist (XCD-sharded atomics) | weight prep | node MLP.
// hist is atomic/latency-bound, MLP is VALU/LDS-bound — complementary block
// types co-schedule on CUs. Node MLP is SINGLE-tile per block (1563 blocks).
// ---------------------------------------------------------------------------
__global__ __launch_bounds__(256) void fused_hist_prep_node_k(
    Ptrs a, const int* __restrict__ eidx, int* __restrict__ cnt8,
    const int* __restrict__ flags,
    u16* __restrict__ img, float* __restrict__ fw,
    u16* __restrict__ hout, int nrows, int G, long E)
{
  const int t = threadIdx.x;
  const int b = blockIdx.x;

  if (b < HIST_BLOCKS) {
    int* cs = cnt8 + (size_t)(b & 7) * G;
    long i = (long)b * 256 + t;
    const long stride = (long)HIST_BLOCKS * 256;
    for (; i < E; i += stride) {
      int tg = eidx[E + i];
      if (tg >= 0 && tg < G) atomicAdd(&cs[tg], 1);
    }
    return;
  }

  if (b < HIST_BLOCKS + PREP_BLOCKS) {
    int i = (b - HIST_BLOCKS) * 256 + t;
    if (i < IMG_TOTAL) {
      const void* bp; int fl; long si; bool real;
      if (i < IMG_MW1) { int nn = i / 72, k = i % 72; bp = a.p[10]; fl = flags[10]; real = k < 64; si = (long)k * 64 + nn; }
      else if (i < IMG_MW2) { int t2 = i - IMG_MW1; int nn = t2 / 136, k = t2 % 136; bp = a.p[12]; fl = flags[12]; real = k < 128; si = (long)k * 64 + nn; }
      else { int t2 = i - IMG_MW2; int nn = t2 / 72, k = t2 % 72; bp = a.p[14]; fl = flags[14]; real = k < 64; si = (long)k * 64 + nn; }
      u16 val = 0;
      if (real) val = f2b(loadF(bp, si, fl));
      img[i] = val;
    } else if (i < IMG_TOTAL + FW_TOTAL) {
      int j = i - IMG_TOTAL;
      const void* bp; int fl; long si;
      if (j < 384)        { bp = a.p[8];  fl = flags[8];  si = j; }
      else if (j < 4480)  { bp = a.p[16]; fl = flags[16]; si = j - 384; }
      else if (j < 8576)  { bp = a.p[18]; fl = flags[18]; si = j - 4480; }
      else {
        int bb = j - 8576; int seg = bb >> 6; si = bb & 63;
        switch (seg) {
          case 0: bp = a.p[17]; fl = flags[17]; break;
          case 1: bp = a.p[19]; fl = flags[19]; break;
          case 2: bp = a.p[9];  fl = flags[9];  break;
          case 3: bp = a.p[11]; fl = flags[11]; break;
          case 4: bp = a.p[13]; fl = flags[13]; break;
          default: bp = a.p[15]; fl = flags[15]; break;
        }
      }
      fw[j] = loadF(bp, si, fl);
    }
    return;
  }

  // ---- node MLP: one 64-row tile per block (max parallelism) ----
  __shared__ float xs[64][68];
  __shared__ float w1s[64][68];
  __shared__ float w2s[64][68];
  __shared__ float b1s[64];
  __shared__ float b2s[64];
  const void* x = a.p[0];
  const int xf = flags[0], f1 = flags[4], fb1 = flags[5], f2 = flags[6], fb2 = flags[7];
  const long rbase = (long)(b - HIST_BLOCKS - PREP_BLOCKS) * 64;
  for (int i = t; i < 4096; i += 256) {
    int k = i >> 6, cc = i & 63;
    w1s[k][cc] = loadF(a.p[4], i, f1);
    w2s[k][cc] = loadF(a.p[6], i, f2);
  }
  if (t < 64) { b1s[t] = loadF(a.p[5], t, fb1); b2s[t] = loadF(a.p[7], t, fb2); }
  {
    int row = t >> 2, ch = t & 3;
    long rg = rbase + row;
    if (rg < nrows) {
      if (xf) {
        const float* xp = (const float*)x + rg * 64 + ch * 16;
#pragma unroll
        for (int m = 0; m < 16; ++m) xs[row][ch * 16 + m] = xp[m];
      } else {
        const u16* xp = (const u16*)x + rg * 64 + ch * 16;
#pragma unroll
        for (int m = 0; m < 16; ++m) xs[row][ch * 16 + m] = b2f(xp[m]);
      }
    } else {
#pragma unroll
      for (int m = 0; m < 16; ++m) xs[row][ch * 16 + m] = 0.f;
    }
  }
  __syncthreads();
  const int r0 = (t >> 4) * 4, c0 = (t & 15) * 4;
  float acc[4][4];
#pragma unroll
  for (int i = 0; i < 4; ++i)
#pragma unroll
    for (int j = 0; j < 4; ++j) acc[i][j] = b1s[c0 + j];
  for (int k = 0; k < 64; ++k) {
    float w0 = w1s[k][c0], w1v = w1s[k][c0 + 1], w2v = w1s[k][c0 + 2], w3v = w1s[k][c0 + 3];
#pragma unroll
    for (int i = 0; i < 4; ++i) {
      float av = xs[r0 + i][k];
      acc[i][0] = fmaf(av, w0, acc[i][0]);
      acc[i][1] = fmaf(av, w1v, acc[i][1]);
      acc[i][2] = fmaf(av, w2v, acc[i][2]);
      acc[i][3] = fmaf(av, w3v, acc[i][3]);
    }
  }
  __syncthreads();
#pragma unroll
  for (int i = 0; i < 4; ++i)
#pragma unroll
    for (int j = 0; j < 4; ++j) xs[r0 + i][c0 + j] = silu_f(acc[i][j]);
  __syncthreads();
  float acc2[4][4];
#pragma unroll
  for (int i = 0; i < 4; ++i)
#pragma unroll
    for (int j = 0; j < 4; ++j) acc2[i][j] = b2s[c0 + j];
  for (int k = 0; k < 64; ++k) {
    float w0 = w2s[k][c0], w1v = w2s[k][c0 + 1], w2v = w2s[k][c0 + 2], w3v = w2s[k][c0 + 3];
#pragma unroll
    for (int i = 0; i < 4; ++i) {
      float av = xs[r0 + i][k];
      acc2[i][0] = fmaf(av, w0, acc2[i][0]);
      acc2[i][1] = fmaf(av, w1v, acc2[i][1]);
      acc2[i][2] = fmaf(av, w2v, acc2[i][2]);
      acc2[i][3] = fmaf(av, w3v, acc2[i][3]);
    }
  }
#pragma unroll
  for (int i = 0; i < 4; ++i) {
    long rg = rbase + r0 + i;
    if (rg < nrows) {
#pragma unroll
      for (int j = 0; j < 4; ++j) hout[rg * 64 + c0 + j] = f2b(acc2[i][j]);
    }
  }
}

// ---------------------------------------------------------------------------
// Kernel 3: scan (8G pairs, target-major) -> cursor8 bases + per-block sums.
// ---------------------------------------------------------------------------
__global__ __launch_bounds__(256) void scan_k(
    const int* __restrict__ cnt8, int* __restrict__ cursor8,
    int* __restrict__ bsum, int G)
{
  const int t = threadIdx.x;
  const int b = blockIdx.x;
  __shared__ int sd[256];
  const long tot = 8L * G;
  long j0 = (long)b * 1024 + (long)t * 4;
  int v[4];
#pragma unroll
  for (int k = 0; k < 4; ++k) {
    long j = j0 + k;
    v[k] = (j < tot) ? cnt8[(size_t)(j & 7) * G + (j >> 3)] : 0;
  }
  int local = v[0] + v[1] + v[2] + v[3];
  sd[t] = local;
  __syncthreads();
  for (int off = 1; off < 256; off <<= 1) {
    int x2 = (t >= off) ? sd[t - off] : 0;
    __syncthreads();
    sd[t] += x2;
    __syncthreads();
  }
  int p = sd[t] - local;
#pragma unroll
  for (int k = 0; k < 4; ++k) {
    long j = j0 + k;
    if (j < tot) cursor8[(size_t)(j & 7) * G + (j >> 3)] = p;
    p += v[k];
  }
  if (t == 255) bsum[b] = sd[255];
}

// ---------------------------------------------------------------------------
// Kernel 4: scatter into sorted order, XCD-sharded cursors; NT stores.
// pack: src (17 bits) | tgt<<17 (15 bits)
// ---------------------------------------------------------------------------
__global__ __launch_bounds__(256) void scat_k(const int* __restrict__ eidx,
                                              int* __restrict__ cursor8,
                                              const int* __restrict__ bsum,
                                              unsigned int* __restrict__ pkS,
                                              int* __restrict__ evp,
                                              long E, int G, int NB2) {
  __shared__ int bo[256];
  const int t = threadIdx.x;
  int v = (t < NB2) ? bsum[t] : 0;
  bo[t] = v;
  __syncthreads();
  for (int off = 1; off < 256; off <<= 1) {
    int x2 = (t >= off) ? bo[t - off] : 0;
    __syncthreads();
    bo[t] += x2;
    __syncthreads();
  }
  if (blockIdx.x == 0 && t == 0) *evp = bo[NB2 - 1];
  int excl = bo[t] - v;
  __syncthreads();
  bo[t] = excl;
  __syncthreads();
  const int c = blockIdx.x & 7;
  int* cur = cursor8 + (size_t)c * G;
  long i = (long)blockIdx.x * 256 + t;
  const long stride = (long)gridDim.x * 256;
  for (; i < E; i += stride) {
    int tg = eidx[E + i];
    if (tg >= 0 && tg < G) {
      int s = eidx[i];
      long j = ((long)tg << 3) | c;
      int p = atomicAdd(&cur[tg], 1) + bo[j >> 10];
      __builtin_nontemporal_store((unsigned int)s | ((unsigned int)tg << 17), pkS + p);
    }
  }
}

// ---------------------------------------------------------------------------
// Kernel 5: edge pipeline — R6/R12 structure + T5 s_setprio around MFMA
// phases. Waves are fully decoupled (zero block barriers in the loop), i.e.
// the exact "wave role diversity" precondition under which setprio measured
// +4-7% (attn, m191) and without which it's null (lockstep GEMM, m190). At
// any instant this CU mixes MFMA-phase and gather/VALU-phase waves;
// setprio(1) lets MFMA-phase waves win issue arbitration. Everything else
// verbatim from R12 (177us, VGPR 64, FETCH 123MB, WRITE 23MB, occ 40% —
// thrice reproduced). If dur stays ~177 within noise, lever inventory is
// exhausted and this decomposition's floor is the unified 128-reg/wave
// budget capping occupancy & ILP.
// ---------------------------------------------------------------------------
#define ETILES 4

__global__ __launch_bounds__(256, 4) void edge_kernel(
    const void* node_pos, const void* grid_pos, const void* orient,
    const unsigned int* __restrict__ pkS, const int* __restrict__ evp,
    const u16* __restrict__ h_node, const u16* __restrict__ img,
    const float* __restrict__ fw, const int* __restrict__ flags,
    float* __restrict__ sums, int G)
{
  __shared__ __align__(16) u16 pool[4][3328];  // per wave 6656 B
  __shared__ float w1e[6][64];
  __shared__ float biasE[4][64];

  const int t = threadIdx.x;
  const int pf = flags[1], gf = flags[2], of = flags[3];
  const int Ev = *evp;

  const int lane = t & 63, w = t >> 6;
  const int q = lane >> 4, c = lane & 15;
  const int m0 = w * 16;
  u16 (* __restrict__ ef1w)[72] = (u16 (*)[72])&pool[w][0];
  u16 (* __restrict__ hAw)[136] = (u16 (*)[136])&pool[w][1152];
  float (* __restrict__ msgfw)[66] = (float (*)[66])&pool[w][1152];  // 4224 <= 4352
  const u16* wE2 = img + IMG_EW2;
  const u16* wM1 = img + IMG_MW1;
  const u16* wM2 = img + IMG_MW2;
  const f32x4 z = {0.f, 0.f, 0.f, 0.f};

  const long blockBase = (long)blockIdx.x * (ETILES * 64);

  // pk words for all tiles in 4 named regs (lane<16 holds edge m0+lane).
  unsigned int pkA = 0, pkB = 0, pkC = 0, pkD = 0;
  if (lane < 16) {
    long e0 = blockBase + m0 + lane;
    if (e0 < Ev)       pkA = pkS[e0];
    if (e0 + 64 < Ev)  pkB = pkS[e0 + 64];
    if (e0 + 128 < Ev) pkC = pkS[e0 + 128];
    if (e0 + 192 < Ev) pkD = pkS[e0 + 192];
  }

  // prefetch state: NAMED scalars only.
  float o0 = 0.f, o1 = 0.f, o2 = 0.f, o3 = 0.f, o4 = 0.f, o5 = 0.f,
        o6 = 0.f, o7 = 0.f, o8 = 0.f;
  float ps0 = 0.f, ps1 = 0.f, ps2 = 0.f, gp0 = 0.f, gp1 = 0.f, gp2 = 0.f;
  short8 hv0, hv1;
  int ptg, ntg;

  // tile-0 prefetch (geometry + h_node + boundary targets)
  {
    int gs = (int)(pkA & 0x1FFFFu);
    int tgc = (int)(pkA >> 17);
    if (lane < 16) {
      ps0 = loadF(node_pos, (long)gs * 3 + 0, pf);
      ps1 = loadF(node_pos, (long)gs * 3 + 1, pf);
      ps2 = loadF(node_pos, (long)gs * 3 + 2, pf);
      gp0 = loadF(grid_pos, (long)tgc * 3 + 0, gf);
      gp1 = loadF(grid_pos, (long)tgc * 3 + 1, gf);
      gp2 = loadF(grid_pos, (long)tgc * 3 + 2, gf);
      o0 = loadF(orient, (long)gs * 9 + 0, of);
      o1 = loadF(orient, (long)gs * 9 + 1, of);
      o2 = loadF(orient, (long)gs * 9 + 2, of);
      o3 = loadF(orient, (long)gs * 9 + 3, of);
      o4 = loadF(orient, (long)gs * 9 + 4, of);
      o5 = loadF(orient, (long)gs * 9 + 5, of);
      o6 = loadF(orient, (long)gs * 9 + 6, of);
      o7 = loadF(orient, (long)gs * 9 + 7, of);
      o8 = loadF(orient, (long)gs * 9 + 8, of);
    }
    unsigned int pks = (unsigned int)__shfl((int)pkA, lane >> 2);
    int ss = (int)(pks & 0x1FFFFu);
    const u16* hp = h_node + (long)ss * 64 + (lane & 3) * 16;
    hv0 = *(const short8*)hp;
    hv1 = *(const short8*)(hp + 8);
    long gPrev = blockBase + m0 - 1;
    long gNext = blockBase + m0 + 16;
    ptg = (gPrev >= 0 && gPrev < Ev) ? (int)(pkS[gPrev] >> 17) : -2;
    ntg = (gNext < Ev) ? (int)(pkS[gNext] >> 17) : -2;
  }

  for (int i = t; i < 384; i += 256) w1e[i / 64][i % 64] = fw[FW_EW1 + i];
  { int seg = t >> 6, cc = t & 63; biasE[seg][cc] = fw[FW_EB1 + seg * 64 + cc]; }
  __syncthreads();   // the ONLY block-wide barrier (shared weights ready)

  for (int tile = 0; tile < ETILES; ++tile) {
    long base = blockBase + (long)tile * 64;
    if (base >= Ev) break;

    // ---- consume + S1 (no cross-wave traffic) ----
    int mytg = -1;
    {
      long eg = base + m0 + lane;
      if (lane < 16) mytg = (eg < Ev) ? (int)(pkA >> 17) : -1;
      // geometry in lanes<16 (garbage elsewhere, unused)
      float rel0 = gp0 - ps0, rel1 = gp1 - ps1, rel2 = gp2 - ps2;
      float tr0 = rel0 * o0; tr0 = fmaf(rel1, o3, tr0); tr0 = fmaf(rel2, o6, tr0);
      float tr1 = rel0 * o1; tr1 = fmaf(rel1, o4, tr1); tr1 = fmaf(rel2, o7, tr1);
      float tr2 = rel0 * o2; tr2 = fmaf(rel1, o5, tr2); tr2 = fmaf(rel2, o8, tr2);
      // broadcast edge attrs: lane e -> lanes 4e..4e+3
      int sl = lane >> 2;
      float a0 = __shfl(ps0, sl), a1 = __shfl(ps1, sl), a2 = __shfl(ps2, sl);
      float a3 = __shfl(tr0, sl), a4 = __shfl(tr1, sl), a5 = __shfl(tr2, sl);
      // h_node staging (wave-private rows)
      int er = lane >> 2, ch = lane & 3;
      *(short8*)&hAw[er][ch * 16] = hv0;
      *(short8*)&hAw[er][ch * 16 + 8] = hv1;
      // S1: edge MLP layer1 (K=6) -> silu -> ef1w (bf16)
      int c0 = (lane & 3) * 16;
      __align__(16) u16 tmp[16];
#pragma unroll
      for (int j = 0; j < 16; ++j) {
        int cc = c0 + j;
        float acc = biasE[0][cc];
        acc = fmaf(a0, w1e[0][cc], acc);
        acc = fmaf(a1, w1e[1][cc], acc);
        acc = fmaf(a2, w1e[2][cc], acc);
        acc = fmaf(a3, w1e[3][cc], acc);
        acc = fmaf(a4, w1e[4][cc], acc);
        acc = fmaf(a5, w1e[5][cc], acc);
        tmp[j] = f2b(silu_f(acc));
      }
      *(short8*)&ef1w[er][c0] = *(const short8*)tmp;
      *(short8*)&ef1w[er][c0 + 8] = *(const short8*)(tmp + 8);
    }
    __builtin_amdgcn_wave_barrier();
    // S2: edge MLP layer2 (K=64) -> hAw cols 64..127  [T5: MFMA-priority]
    {
      short8 a0 = *(const short8*)&ef1w[c][q * 8];
      short8 a1 = *(const short8*)&ef1w[c][32 + q * 8];
      __builtin_amdgcn_s_setprio(1);
#pragma unroll
      for (int nt = 0; nt < 4; ++nt) {
        short8 b0 = *(const short8*)&wE2[(nt * 16 + c) * 72 + q * 8];
        short8 b1v = *(const short8*)&wE2[(nt * 16 + c) * 72 + 32 + q * 8];
        f32x4 acc = __builtin_amdgcn_mfma_f32_16x16x32_bf16(a0, b0, z, 0, 0, 0);
        acc = __builtin_amdgcn_mfma_f32_16x16x32_bf16(a1, b1v, acc, 0, 0, 0);
#pragma unroll
        for (int r = 0; r < 4; ++r) {
          int row = q * 4 + r, col = nt * 16 + c;
          hAw[row][64 + col] = f2b(acc[r] + biasE[1][col]);
        }
      }
      __builtin_amdgcn_s_setprio(0);
    }
    __builtin_amdgcn_wave_barrier();
    // S3: msg MLP layer1 (K=128) -> silu -> ef1w  [T5: MFMA-priority]
    {
      short8 a0 = *(const short8*)&hAw[c][q * 8];
      short8 a1 = *(const short8*)&hAw[c][32 + q * 8];
      short8 a2 = *(const short8*)&hAw[c][64 + q * 8];
      short8 a3 = *(const short8*)&hAw[c][96 + q * 8];
      __builtin_amdgcn_s_setprio(1);
#pragma unroll
      for (int nt = 0; nt < 4; ++nt) {
        const u16* wp = &wM1[(nt * 16 + c) * 136];
        f32x4 acc = __builtin_amdgcn_mfma_f32_16x16x32_bf16(a0, *(const short8*)(wp + q * 8), z, 0, 0, 0);
        acc = __builtin_amdgcn_mfma_f32_16x16x32_bf16(a1, *(const short8*)(wp + 32 + q * 8), acc, 0, 0, 0);
        acc = __builtin_amdgcn_mfma_f32_16x16x32_bf16(a2, *(const short8*)(wp + 64 + q * 8), acc, 0, 0, 0);
        acc = __builtin_amdgcn_mfma_f32_16x16x32_bf16(a3, *(const short8*)(wp + 96 + q * 8), acc, 0, 0, 0);
#pragma unroll
        for (int r = 0; r < 4; ++r) {
          int row = q * 4 + r, col = nt * 16 + c;
          ef1w[row][col] = f2b(silu_f(acc[r] + biasE[2][col]));
        }
      }
      __builtin_amdgcn_s_setprio(0);
    }
    __builtin_amdgcn_wave_barrier();   // hAw reads done; msgfw may overlay
    // S4: msg MLP layer2 (K=64) -> msgfw (f32, +bias)  [T5: MFMA-priority]
    {
      short8 a0 = *(const short8*)&ef1w[c][q * 8];
      short8 a1 = *(const short8*)&ef1w[c][32 + q * 8];
      __builtin_amdgcn_wave_barrier();   // pin reads before overlay writes
      __builtin_amdgcn_s_setprio(1);
#pragma unroll
      for (int nt = 0; nt < 4; ++nt) {
        short8 b0 = *(const short8*)&wM2[(nt * 16 + c) * 72 + q * 8];
        short8 b1v = *(const short8*)&wM2[(nt * 16 + c) * 72 + 32 + q * 8];
        f32x4 acc = __builtin_amdgcn_mfma_f32_16x16x32_bf16(a0, b0, z, 0, 0, 0);
        acc = __builtin_amdgcn_mfma_f32_16x16x32_bf16(a1, b1v, acc, 0, 0, 0);
#pragma unroll
        for (int r = 0; r < 4; ++r) {
          int row = q * 4 + r, col = nt * 16 + c;
          msgfw[row][col] = acc[r] + biasE[3][col];
        }
      }
      __builtin_amdgcn_s_setprio(0);
    }
    __builtin_amdgcn_wave_barrier();

    // Issue next tile's geometry + h_node gathers; in flight across reduce,
    // waited at next tile's consume (register use). ptg/ntg NOT touched here
    // (still needed by this tile's reduce).
    __builtin_amdgcn_sched_barrier(0);
    if (tile + 1 < ETILES && base + 64 < Ev) {
      int gs2 = (int)(pkB & 0x1FFFFu);
      int tgc2 = (int)(pkB >> 17);
      if (lane < 16) {
        ps0 = loadF(node_pos, (long)gs2 * 3 + 0, pf);
        ps1 = loadF(node_pos, (long)gs2 * 3 + 1, pf);
        ps2 = loadF(node_pos, (long)gs2 * 3 + 2, pf);
        gp0 = loadF(grid_pos, (long)tgc2 * 3 + 0, gf);
        gp1 = loadF(grid_pos, (long)tgc2 * 3 + 1, gf);
        gp2 = loadF(grid_pos, (long)tgc2 * 3 + 2, gf);
        o0 = loadF(orient, (long)gs2 * 9 + 0, of);
        o1 = loadF(orient, (long)gs2 * 9 + 1, of);
        o2 = loadF(orient, (long)gs2 * 9 + 2, of);
        o3 = loadF(orient, (long)gs2 * 9 + 3, of);
        o4 = loadF(orient, (long)gs2 * 9 + 4, of);
        o5 = loadF(orient, (long)gs2 * 9 + 5, of);
        o6 = loadF(orient, (long)gs2 * 9 + 6, of);
        o7 = loadF(orient, (long)gs2 * 9 + 7, of);
        o8 = loadF(orient, (long)gs2 * 9 + 8, of);
      }
      unsigned int pks2 = (unsigned int)__shfl((int)pkB, lane >> 2);
      int ss2 = (int)(pks2 & 0x1FFFFu);
      const u16* hp2 = h_node + (long)ss2 * 64 + (lane & 3) * 16;
      hv0 = *(const short8*)hp2;
      hv1 = *(const short8*)(hp2 + 8);
    }
    __builtin_amdgcn_sched_barrier(0);

    // Run-reduction over the wave's 16 rows; col = lane. Targets via shfl
    // from lane r's mytg; boundary targets ptg/ntg from pkS (exact, so
    // atomic vs exclusive-store is positional & timing-independent).
    {
      int col = lane;
      int cur = __shfl(mytg, 0);
      float run = msgfw[0][col];
      bool lopen = (ptg == cur);
#pragma unroll
      for (int r2 = 1; r2 < 16; ++r2) {
        int tg = __shfl(mytg, r2);
        float v = msgfw[r2][col];
        if (tg == cur) {
          run += v;
        } else {
          if (cur >= 0) {
            if (lopen) unsafeAtomicAdd(&sums[(long)cur * 64 + col], run);
            else sums[(long)cur * 64 + col] = run;
          }
          cur = tg; run = v; lopen = false;
        }
      }
      bool ropen = (ntg == cur);
      if (cur >= 0) {
        if (lopen || ropen) unsafeAtomicAdd(&sums[(long)cur * 64 + col], run);
        else sums[(long)cur * 64 + col] = run;
      }
    }
    __builtin_amdgcn_wave_barrier();   // msgfw reads before next consume's hAw writes

    // boundary targets for next tile (reduce done; safe to overwrite)
    if (tile + 1 < ETILES && base + 64 < Ev) {
      long gPrev = base + 64 + m0 - 1;      // >= 63, always valid index
      long gNext = base + 64 + m0 + 16;
      ptg = (gPrev < Ev) ? (int)(pkS[gPrev] >> 17) : -2;
      ntg = (gNext < Ev) ? (int)(pkS[gNext] >> 17) : -2;
    }
    pkA = pkB; pkB = pkC; pkC = pkD;
  }
}

// ---------------------------------------------------------------------------
// Kernel 6: scatter-mean (sum of 8 count shards) + update MLP -> f32 out.
// One 64-row tile per block (512 blocks).
// ---------------------------------------------------------------------------
__global__ __launch_bounds__(256) void upd_mlp(
    const float* __restrict__ sums, const int* __restrict__ cnt8,
    const float* __restrict__ fw, float* __restrict__ out, int nrows)
{
  __shared__ float xs[64][68];
  __shared__ float w1s[64][68];
  __shared__ float w2s[64][68];
  __shared__ float b1s[64];
  __shared__ float b2s[64];
  const int t = threadIdx.x;
  const long rbase = (long)blockIdx.x * 64;
  for (int i = t; i < 4096; i += 256) {
    int k = i >> 6, cc = i & 63;
    w1s[k][cc] = fw[FW_UW1 + i];
    w2s[k][cc] = fw[FW_UW2 + i];
  }
  if (t < 64) { b1s[t] = fw[FW_UB1 + t]; b2s[t] = fw[FW_UB2 + t]; }
  {
    int row = t >> 2, ch = t & 3;
    long rg = rbase + row;
    if (rg < nrows) {
      int cn = 0;
#pragma unroll
      for (int cc = 0; cc < 8; ++cc) cn += cnt8[(size_t)cc * nrows + rg];
      float inv = 1.0f / fmaxf((float)cn, 1.0f);
      const float* p = sums + rg * 64 + ch * 16;
#pragma unroll
      for (int m = 0; m < 16; ++m) xs[row][ch * 16 + m] = p[m] * inv;
    } else {
#pragma unroll
      for (int m = 0; m < 16; ++m) xs[row][ch * 16 + m] = 0.f;
    }
  }
  __syncthreads();
  const int r0 = (t >> 4) * 4, c0 = (t & 15) * 4;
  float acc[4][4];
#pragma unroll
  for (int i = 0; i < 4; ++i)
#pragma unroll
    for (int j = 0; j < 4; ++j) acc[i][j] = b1s[c0 + j];
  for (int k = 0; k < 64; ++k) {
    float w0 = w1s[k][c0], w1v = w1s[k][c0 + 1], w2v = w1s[k][c0 + 2], w3v = w1s[k][c0 + 3];
#pragma unroll
    for (int i = 0; i < 4; ++i) {
      float av = xs[r0 + i][k];
      acc[i][0] = fmaf(av, w0, acc[i][0]);
      acc[i][1] = fmaf(av, w1v, acc[i][1]);
      acc[i][2] = fmaf(av, w2v, acc[i][2]);
      acc[i][3] = fmaf(av, w3v, acc[i][3]);
    }
  }
  __syncthreads();
#pragma unroll
  for (int i = 0; i < 4; ++i)
#pragma unroll
    for (int j = 0; j < 4; ++j) xs[r0 + i][c0 + j] = silu_f(acc[i][j]);
  __syncthreads();
  float acc2[4][4];
#pragma unroll
  for (int i = 0; i < 4; ++i)
#pragma unroll
    for (int j = 0; j < 4; ++j) acc2[i][j] = b2s[c0 + j];
  for (int k = 0; k < 64; ++k) {
    float w0 = w2s[k][c0], w1v = w2s[k][c0 + 1], w2v = w2s[k][c0 + 2], w3v = w2s[k][c0 + 3];
#pragma unroll
    for (int i = 0; i < 4; ++i) {
      float av = xs[r0 + i][k];
      acc2[i][0] = fmaf(av, w0, acc2[i][0]);
      acc2[i][1] = fmaf(av, w1v, acc2[i][1]);
      acc2[i][2] = fmaf(av, w2v, acc2[i][2]);
      acc2[i][3] = fmaf(av, w3v, acc2[i][3]);
    }
  }
#pragma unroll
  for (int i = 0; i < 4; ++i) {
    long rg = rbase + r0 + i;
    if (rg < nrows) {
#pragma unroll
      for (int j = 0; j < 4; ++j) out[rg * 64 + c0 + j] = acc2[i][j];
    }
  }
}

// ---------------------------------------------------------------------------
extern "C" void kernel_launch(void* const* d_in, const int* in_sizes, int n_in,
                              void* d_out, int out_size, void* d_ws, size_t ws_size,
                              hipStream_t stream) {
  const int N = in_sizes[1] / 3;
  const int G = in_sizes[2] / 3;
  const long E = (long)in_sizes[4] / 2;
  const int NB2 = (int)((8L * G + 1023) / 1024);   // <=256 for G<=32768
  const int nodeBlocks = (N + 63) / 64;

  char* ws = (char*)d_ws;
  float* sums = (float*)ws;
  size_t off = (size_t)G * 256;
  int* cnt8 = (int*)(ws + off);     off += (size_t)G * 32;   // 8 shards
  int* cursor8 = (int*)(ws + off);  off += (size_t)G * 32;
  int* bsum = (int*)(ws + off);     off += 1024;
  int* evp = (int*)(ws + off);      off += 256;
  int* flags = (int*)(ws + off);    off += 256;
  unsigned int* pkS = (unsigned int*)(ws + off); off += (size_t)E * 4;
  u16* h_node = (u16*)(ws + off);   off += (size_t)N * 128;
  u16* img = (u16*)(ws + off);      off += (size_t)IMG_TOTAL * 2;
  float* fw = (float*)(ws + off);

  // zero sums + cnt8 (ws poisoned 0xAA before every timed launch)
  hipMemsetAsync(ws, 0, (size_t)G * 288, stream);

  Ptrs a;
  const int map[20] = {0,1,2,3, 5,6,7,8, 9,10,11,12, 13,14,15,16, 17,18,19,20};
  for (int i = 0; i < 20; ++i) { a.p[i] = d_in[map[i]]; a.n[i] = in_sizes[map[i]]; }

  detect_k<<<20, 256, 0, stream>>>(a, flags);
  fused_hist_prep_node_k<<<HIST_BLOCKS + PREP_BLOCKS + nodeBlocks, 256, 0, stream>>>(
      a, (const int*)d_in[4], cnt8, flags, img, fw, h_node, N, G, E);
  scan_k<<<NB2, 256, 0, stream>>>(cnt8, cursor8, bsum, G);
  scat_k<<<1024, 256, 0, stream>>>((const int*)d_in[4], cursor8, bsum, pkS, evp, E, G, NB2);
  edge_kernel<<<(int)((E + ETILES * 64 - 1) / (ETILES * 64)), 256, 0, stream>>>(
      d_in[1], d_in[2], d_in[3], pkS, evp, h_node, img, fw, flags, sums, G);
  upd_mlp<<<(G + 63) / 64, 256, 0, stream>>>(sums, cnt8, fw, (float*)d_out, G);
}

// Round 14
// 442.314 us; speedup vs baseline: 1.1542x; 1.1542x over previous
//
#include <hip/hip_runtime.h>
#include <hip/hip_bf16.h>
#include <cstdint>

typedef __attribute__((ext_vector_type(8))) short short8;
typedef __attribute__((ext_vector_type(4))) float f32x4;
typedef unsigned short u16;

__device__ __forceinline__ float b2f(u16 u) {
  union { unsigned int i; float f; } v; v.i = ((unsigned int)u) << 16; return v.f;
}
// hardware RNE f32->bf16
__device__ __forceinline__ u16 f2b(float f) {
  __hip_bfloat16 h = __float2bfloat16(f);
  union { __hip_bfloat16 h; u16 u; } v; v.h = h; return v.u;
}
// silu via v_rcp_f32 (<=1ulp) instead of full-precision divide (~12 inst).
__device__ __forceinline__ float silu_f(float x) {
  return x * __builtin_amdgcn_rcpf(1.0f + __expf(-x));
}

__device__ __forceinline__ float loadF(const void* p, long i, int isf32) {
  if (isf32) return ((const float*)p)[i];
  return b2f(((const u16*)p)[i]);
}

// dtype sniff bit: f32 data viewed as u16 -> low halves are ~uniform-random;
// ~50% land outside bf16-exponent [2^-63, 2^65). Genuine bf16 N(0,1)/uniform
// data: none (zeros excluded).
__device__ __forceinline__ int sniffbit(u16 u) {
  unsigned e = (u >> 7) & 0xffu;
  return (e >= 0xC0u || (e < 0x40u && (u & 0x7fffu) != 0)) ? 1 : 0;
}

struct Ptrs { const void* p[20]; int n[20]; };

// f32 prepped-weight layout (float offsets)
#define FW_EW1 0
#define FW_UW1 384
#define FW_UW2 4480
#define FW_UB1 8576
#define FW_UB2 8640
#define FW_EB1 8704
#define FW_EB2 8768
#define FW_MB1 8832
#define FW_MB2 8896
#define FW_TOTAL 8960

// bf16 transposed image layout (u16 offsets)
#define IMG_EW2 0
#define IMG_MW1 4608
#define IMG_MW2 13312
#define IMG_TOTAL 17920

#define PREP_BLOCKS 105   // ceil((IMG_TOTAL + FW_TOTAL)/256)
#define HIST_BLOCKS 1024

// ---------------------------------------------------------------------------
// Kernel 1: dtype detection ONLY (tiny, ~3us). Lets K2 run hist CONCURRENTLY
// with prep + node-MLP (which need flags, not the histogram).
// ---------------------------------------------------------------------------
__global__ __launch_bounds__(256) void detect_k(Ptrs a, int* __restrict__ flags)
{
  const int t = threadIdx.x;
  const int j = blockIdx.x;
  const u16* q = (const u16*)a.p[j];
  int n = a.n[j];
  int m = n < 4096 ? n : 4096;
  int cnt = 0;
  for (int i = t; i < m; i += 256) cnt += sniffbit(q[i]);
  __shared__ int tot;
  if (t == 0) tot = 0;
  __syncthreads();
  if (cnt) atomicAdd(&tot, cnt);
  __syncthreads();
  if (t == 0) flags[j] = (tot >= 2) ? 1 : 0;
}

// ---------------------------------------------------------------------------
// Kernel 2: FUSED hist (XCD-sharded atomics) | weight prep | node MLP.
// hist is atomic/latency-bound, MLP is VALU/LDS-bound — complementary block
// types co-schedule on CUs. Node MLP is SINGLE-tile per block (1563 blocks).
// ---------------------------------------------------------------------------
__global__ __launch_bounds__(256) void fused_hist_prep_node_k(
    Ptrs a, const int* __restrict__ eidx, int* __restrict__ cnt8,
    const int* __restrict__ flags,
    u16* __restrict__ img, float* __restrict__ fw,
    u16* __restrict__ hout, int nrows, int G, long E)
{
  const int t = threadIdx.x;
  const int b = blockIdx.x;

  if (b < HIST_BLOCKS) {
    int* cs = cnt8 + (size_t)(b & 7) * G;
    long i = (long)b * 256 + t;
    const long stride = (long)HIST_BLOCKS * 256;
    for (; i < E; i += stride) {
      int tg = eidx[E + i];
      if (tg >= 0 && tg < G) atomicAdd(&cs[tg], 1);
    }
    return;
  }

  if (b < HIST_BLOCKS + PREP_BLOCKS) {
    int i = (b - HIST_BLOCKS) * 256 + t;
    if (i < IMG_TOTAL) {
      const void* bp; int fl; long si; bool real;
      if (i < IMG_MW1) { int nn = i / 72, k = i % 72; bp = a.p[10]; fl = flags[10]; real = k < 64; si = (long)k * 64 + nn; }
      else if (i < IMG_MW2) { int t2 = i - IMG_MW1; int nn = t2 / 136, k = t2 % 136; bp = a.p[12]; fl = flags[12]; real = k < 128; si = (long)k * 64 + nn; }
      else { int t2 = i - IMG_MW2; int nn = t2 / 72, k = t2 % 72; bp = a.p[14]; fl = flags[14]; real = k < 64; si = (long)k * 64 + nn; }
      u16 val = 0;
      if (real) val = f2b(loadF(bp, si, fl));
      img[i] = val;
    } else if (i < IMG_TOTAL + FW_TOTAL) {
      int j = i - IMG_TOTAL;
      const void* bp; int fl; long si;
      if (j < 384)        { bp = a.p[8];  fl = flags[8];  si = j; }
      else if (j < 4480)  { bp = a.p[16]; fl = flags[16]; si = j - 384; }
      else if (j < 8576)  { bp = a.p[18]; fl = flags[18]; si = j - 4480; }
      else {
        int bb = j - 8576; int seg = bb >> 6; si = bb & 63;
        switch (seg) {
          case 0: bp = a.p[17]; fl = flags[17]; break;
          case 1: bp = a.p[19]; fl = flags[19]; break;
          case 2: bp = a.p[9];  fl = flags[9];  break;
          case 3: bp = a.p[11]; fl = flags[11]; break;
          case 4: bp = a.p[13]; fl = flags[13]; break;
          default: bp = a.p[15]; fl = flags[15]; break;
        }
      }
      fw[j] = loadF(bp, si, fl);
    }
    return;
  }

  // ---- node MLP: one 64-row tile per block (max parallelism) ----
  __shared__ float xs[64][68];
  __shared__ float w1s[64][68];
  __shared__ float w2s[64][68];
  __shared__ float b1s[64];
  __shared__ float b2s[64];
  const void* x = a.p[0];
  const int xf = flags[0], f1 = flags[4], fb1 = flags[5], f2 = flags[6], fb2 = flags[7];
  const long rbase = (long)(b - HIST_BLOCKS - PREP_BLOCKS) * 64;
  for (int i = t; i < 4096; i += 256) {
    int k = i >> 6, cc = i & 63;
    w1s[k][cc] = loadF(a.p[4], i, f1);
    w2s[k][cc] = loadF(a.p[6], i, f2);
  }
  if (t < 64) { b1s[t] = loadF(a.p[5], t, fb1); b2s[t] = loadF(a.p[7], t, fb2); }
  {
    int row = t >> 2, ch = t & 3;
    long rg = rbase + row;
    if (rg < nrows) {
      if (xf) {
        const float* xp = (const float*)x + rg * 64 + ch * 16;
#pragma unroll
        for (int m = 0; m < 16; ++m) xs[row][ch * 16 + m] = xp[m];
      } else {
        const u16* xp = (const u16*)x + rg * 64 + ch * 16;
#pragma unroll
        for (int m = 0; m < 16; ++m) xs[row][ch * 16 + m] = b2f(xp[m]);
      }
    } else {
#pragma unroll
      for (int m = 0; m < 16; ++m) xs[row][ch * 16 + m] = 0.f;
    }
  }
  __syncthreads();
  const int r0 = (t >> 4) * 4, c0 = (t & 15) * 4;
  float acc[4][4];
#pragma unroll
  for (int i = 0; i < 4; ++i)
#pragma unroll
    for (int j = 0; j < 4; ++j) acc[i][j] = b1s[c0 + j];
  for (int k = 0; k < 64; ++k) {
    float w0 = w1s[k][c0], w1v = w1s[k][c0 + 1], w2v = w1s[k][c0 + 2], w3v = w1s[k][c0 + 3];
#pragma unroll
    for (int i = 0; i < 4; ++i) {
      float av = xs[r0 + i][k];
      acc[i][0] = fmaf(av, w0, acc[i][0]);
      acc[i][1] = fmaf(av, w1v, acc[i][1]);
      acc[i][2] = fmaf(av, w2v, acc[i][2]);
      acc[i][3] = fmaf(av, w3v, acc[i][3]);
    }
  }
  __syncthreads();
#pragma unroll
  for (int i = 0; i < 4; ++i)
#pragma unroll
    for (int j = 0; j < 4; ++j) xs[r0 + i][c0 + j] = silu_f(acc[i][j]);
  __syncthreads();
  float acc2[4][4];
#pragma unroll
  for (int i = 0; i < 4; ++i)
#pragma unroll
    for (int j = 0; j < 4; ++j) acc2[i][j] = b2s[c0 + j];
  for (int k = 0; k < 64; ++k) {
    float w0 = w2s[k][c0], w1v = w2s[k][c0 + 1], w2v = w2s[k][c0 + 2], w3v = w2s[k][c0 + 3];
#pragma unroll
    for (int i = 0; i < 4; ++i) {
      float av = xs[r0 + i][k];
      acc2[i][0] = fmaf(av, w0, acc2[i][0]);
      acc2[i][1] = fmaf(av, w1v, acc2[i][1]);
      acc2[i][2] = fmaf(av, w2v, acc2[i][2]);
      acc2[i][3] = fmaf(av, w3v, acc2[i][3]);
    }
  }
#pragma unroll
  for (int i = 0; i < 4; ++i) {
    long rg = rbase + r0 + i;
    if (rg < nrows) {
#pragma unroll
      for (int j = 0; j < 4; ++j) hout[rg * 64 + c0 + j] = f2b(acc2[i][j]);
    }
  }
}

// ---------------------------------------------------------------------------
// Kernel 3: scan (8G pairs, target-major) -> cursor8 bases + per-block sums.
// ---------------------------------------------------------------------------
__global__ __launch_bounds__(256) void scan_k(
    const int* __restrict__ cnt8, int* __restrict__ cursor8,
    int* __restrict__ bsum, int G)
{
  const int t = threadIdx.x;
  const int b = blockIdx.x;
  __shared__ int sd[256];
  const long tot = 8L * G;
  long j0 = (long)b * 1024 + (long)t * 4;
  int v[4];
#pragma unroll
  for (int k = 0; k < 4; ++k) {
    long j = j0 + k;
    v[k] = (j < tot) ? cnt8[(size_t)(j & 7) * G + (j >> 3)] : 0;
  }
  int local = v[0] + v[1] + v[2] + v[3];
  sd[t] = local;
  __syncthreads();
  for (int off = 1; off < 256; off <<= 1) {
    int x2 = (t >= off) ? sd[t - off] : 0;
    __syncthreads();
    sd[t] += x2;
    __syncthreads();
  }
  int p = sd[t] - local;
#pragma unroll
  for (int k = 0; k < 4; ++k) {
    long j = j0 + k;
    if (j < tot) cursor8[(size_t)(j & 7) * G + (j >> 3)] = p;
    p += v[k];
  }
  if (t == 255) bsum[b] = sd[255];
}

// ---------------------------------------------------------------------------
// Kernel 4: scatter into sorted order, XCD-sharded cursors; NT stores.
// pack: src (17 bits) | tgt<<17 (15 bits)
// ---------------------------------------------------------------------------
__global__ __launch_bounds__(256) void scat_k(const int* __restrict__ eidx,
                                              int* __restrict__ cursor8,
                                              const int* __restrict__ bsum,
                                              unsigned int* __restrict__ pkS,
                                              int* __restrict__ evp,
                                              long E, int G, int NB2) {
  __shared__ int bo[256];
  const int t = threadIdx.x;
  int v = (t < NB2) ? bsum[t] : 0;
  bo[t] = v;
  __syncthreads();
  for (int off = 1; off < 256; off <<= 1) {
    int x2 = (t >= off) ? bo[t - off] : 0;
    __syncthreads();
    bo[t] += x2;
    __syncthreads();
  }
  if (blockIdx.x == 0 && t == 0) *evp = bo[NB2 - 1];
  int excl = bo[t] - v;
  __syncthreads();
  bo[t] = excl;
  __syncthreads();
  const int c = blockIdx.x & 7;
  int* cur = cursor8 + (size_t)c * G;
  long i = (long)blockIdx.x * 256 + t;
  const long stride = (long)gridDim.x * 256;
  for (; i < E; i += stride) {
    int tg = eidx[E + i];
    if (tg >= 0 && tg < G) {
      int s = eidx[i];
      long j = ((long)tg << 3) | c;
      int p = atomicAdd(&cur[tg], 1) + bo[j >> 10];
      __builtin_nontemporal_store((unsigned int)s | ((unsigned int)tg << 17), pkS + p);
    }
  }
}

// ---------------------------------------------------------------------------
// Kernel 5: edge pipeline — R6/R12 structure, FINAL (177us, VGPR 64, FETCH
// 123MB, WRITE 23MB, occ 40%; reproduced 3x). Barrier-free wave-decoupled:
// per-wave targets via __shfl; boundary targets ptg/ntg from pkS; geometry
// broadcast via __shfl; all LDS wave-private; geometry + h_node register
// prefetch under (256,4)'s 128-reg budget. Falsified escape attempts: R7
// LDS-trim, R8 (256,5) squeeze (spill), R9 MLP tiling, R11 dual-stream
// (spill), R13 setprio (regalloc perturbation -> spill). The kernel sits
// exactly at unified-register-file capacity, which caps both occupancy and
// ILP depth — the structural floor for this decomposition at HIP source.
// ---------------------------------------------------------------------------
#define ETILES 4

__global__ __launch_bounds__(256, 4) void edge_kernel(
    const void* node_pos, const void* grid_pos, const void* orient,
    const unsigned int* __restrict__ pkS, const int* __restrict__ evp,
    const u16* __restrict__ h_node, const u16* __restrict__ img,
    const float* __restrict__ fw, const int* __restrict__ flags,
    float* __restrict__ sums, int G)
{
  __shared__ __align__(16) u16 pool[4][3328];  // per wave 6656 B
  __shared__ float w1e[6][64];
  __shared__ float biasE[4][64];

  const int t = threadIdx.x;
  const int pf = flags[1], gf = flags[2], of = flags[3];
  const int Ev = *evp;

  const int lane = t & 63, w = t >> 6;
  const int q = lane >> 4, c = lane & 15;
  const int m0 = w * 16;
  u16 (* __restrict__ ef1w)[72] = (u16 (*)[72])&pool[w][0];
  u16 (* __restrict__ hAw)[136] = (u16 (*)[136])&pool[w][1152];
  float (* __restrict__ msgfw)[66] = (float (*)[66])&pool[w][1152];  // 4224 <= 4352
  const u16* wE2 = img + IMG_EW2;
  const u16* wM1 = img + IMG_MW1;
  const u16* wM2 = img + IMG_MW2;
  const f32x4 z = {0.f, 0.f, 0.f, 0.f};

  const long blockBase = (long)blockIdx.x * (ETILES * 64);

  // pk words for all tiles in 4 named regs (lane<16 holds edge m0+lane).
  unsigned int pkA = 0, pkB = 0, pkC = 0, pkD = 0;
  if (lane < 16) {
    long e0 = blockBase + m0 + lane;
    if (e0 < Ev)       pkA = pkS[e0];
    if (e0 + 64 < Ev)  pkB = pkS[e0 + 64];
    if (e0 + 128 < Ev) pkC = pkS[e0 + 128];
    if (e0 + 192 < Ev) pkD = pkS[e0 + 192];
  }

  // prefetch state: NAMED scalars only.
  float o0 = 0.f, o1 = 0.f, o2 = 0.f, o3 = 0.f, o4 = 0.f, o5 = 0.f,
        o6 = 0.f, o7 = 0.f, o8 = 0.f;
  float ps0 = 0.f, ps1 = 0.f, ps2 = 0.f, gp0 = 0.f, gp1 = 0.f, gp2 = 0.f;
  short8 hv0, hv1;
  int ptg, ntg;

  // tile-0 prefetch (geometry + h_node + boundary targets)
  {
    int gs = (int)(pkA & 0x1FFFFu);
    int tgc = (int)(pkA >> 17);
    if (lane < 16) {
      ps0 = loadF(node_pos, (long)gs * 3 + 0, pf);
      ps1 = loadF(node_pos, (long)gs * 3 + 1, pf);
      ps2 = loadF(node_pos, (long)gs * 3 + 2, pf);
      gp0 = loadF(grid_pos, (long)tgc * 3 + 0, gf);
      gp1 = loadF(grid_pos, (long)tgc * 3 + 1, gf);
      gp2 = loadF(grid_pos, (long)tgc * 3 + 2, gf);
      o0 = loadF(orient, (long)gs * 9 + 0, of);
      o1 = loadF(orient, (long)gs * 9 + 1, of);
      o2 = loadF(orient, (long)gs * 9 + 2, of);
      o3 = loadF(orient, (long)gs * 9 + 3, of);
      o4 = loadF(orient, (long)gs * 9 + 4, of);
      o5 = loadF(orient, (long)gs * 9 + 5, of);
      o6 = loadF(orient, (long)gs * 9 + 6, of);
      o7 = loadF(orient, (long)gs * 9 + 7, of);
      o8 = loadF(orient, (long)gs * 9 + 8, of);
    }
    unsigned int pks = (unsigned int)__shfl((int)pkA, lane >> 2);
    int ss = (int)(pks & 0x1FFFFu);
    const u16* hp = h_node + (long)ss * 64 + (lane & 3) * 16;
    hv0 = *(const short8*)hp;
    hv1 = *(const short8*)(hp + 8);
    long gPrev = blockBase + m0 - 1;
    long gNext = blockBase + m0 + 16;
    ptg = (gPrev >= 0 && gPrev < Ev) ? (int)(pkS[gPrev] >> 17) : -2;
    ntg = (gNext < Ev) ? (int)(pkS[gNext] >> 17) : -2;
  }

  for (int i = t; i < 384; i += 256) w1e[i / 64][i % 64] = fw[FW_EW1 + i];
  { int seg = t >> 6, cc = t & 63; biasE[seg][cc] = fw[FW_EB1 + seg * 64 + cc]; }
  __syncthreads();   // the ONLY block-wide barrier (shared weights ready)

  for (int tile = 0; tile < ETILES; ++tile) {
    long base = blockBase + (long)tile * 64;
    if (base >= Ev) break;

    // ---- consume + S1 (no cross-wave traffic) ----
    int mytg = -1;
    {
      long eg = base + m0 + lane;
      if (lane < 16) mytg = (eg < Ev) ? (int)(pkA >> 17) : -1;
      // geometry in lanes<16 (garbage elsewhere, unused)
      float rel0 = gp0 - ps0, rel1 = gp1 - ps1, rel2 = gp2 - ps2;
      float tr0 = rel0 * o0; tr0 = fmaf(rel1, o3, tr0); tr0 = fmaf(rel2, o6, tr0);
      float tr1 = rel0 * o1; tr1 = fmaf(rel1, o4, tr1); tr1 = fmaf(rel2, o7, tr1);
      float tr2 = rel0 * o2; tr2 = fmaf(rel1, o5, tr2); tr2 = fmaf(rel2, o8, tr2);
      // broadcast edge attrs: lane e -> lanes 4e..4e+3
      int sl = lane >> 2;
      float a0 = __shfl(ps0, sl), a1 = __shfl(ps1, sl), a2 = __shfl(ps2, sl);
      float a3 = __shfl(tr0, sl), a4 = __shfl(tr1, sl), a5 = __shfl(tr2, sl);
      // h_node staging (wave-private rows)
      int er = lane >> 2, ch = lane & 3;
      *(short8*)&hAw[er][ch * 16] = hv0;
      *(short8*)&hAw[er][ch * 16 + 8] = hv1;
      // S1: edge MLP layer1 (K=6) -> silu -> ef1w (bf16)
      int c0 = (lane & 3) * 16;
      __align__(16) u16 tmp[16];
#pragma unroll
      for (int j = 0; j < 16; ++j) {
        int cc = c0 + j;
        float acc = biasE[0][cc];
        acc = fmaf(a0, w1e[0][cc], acc);
        acc = fmaf(a1, w1e[1][cc], acc);
        acc = fmaf(a2, w1e[2][cc], acc);
        acc = fmaf(a3, w1e[3][cc], acc);
        acc = fmaf(a4, w1e[4][cc], acc);
        acc = fmaf(a5, w1e[5][cc], acc);
        tmp[j] = f2b(silu_f(acc));
      }
      *(short8*)&ef1w[er][c0] = *(const short8*)tmp;
      *(short8*)&ef1w[er][c0 + 8] = *(const short8*)(tmp + 8);
    }
    __builtin_amdgcn_wave_barrier();
    // S2: edge MLP layer2 (K=64) -> hAw cols 64..127
    {
      short8 a0 = *(const short8*)&ef1w[c][q * 8];
      short8 a1 = *(const short8*)&ef1w[c][32 + q * 8];
#pragma unroll
      for (int nt = 0; nt < 4; ++nt) {
        short8 b0 = *(const short8*)&wE2[(nt * 16 + c) * 72 + q * 8];
        short8 b1v = *(const short8*)&wE2[(nt * 16 + c) * 72 + 32 + q * 8];
        f32x4 acc = __builtin_amdgcn_mfma_f32_16x16x32_bf16(a0, b0, z, 0, 0, 0);
        acc = __builtin_amdgcn_mfma_f32_16x16x32_bf16(a1, b1v, acc, 0, 0, 0);
#pragma unroll
        for (int r = 0; r < 4; ++r) {
          int row = q * 4 + r, col = nt * 16 + c;
          hAw[row][64 + col] = f2b(acc[r] + biasE[1][col]);
        }
      }
    }
    __builtin_amdgcn_wave_barrier();
    // S3: msg MLP layer1 (K=128) -> silu -> ef1w
    {
      short8 a0 = *(const short8*)&hAw[c][q * 8];
      short8 a1 = *(const short8*)&hAw[c][32 + q * 8];
      short8 a2 = *(const short8*)&hAw[c][64 + q * 8];
      short8 a3 = *(const short8*)&hAw[c][96 + q * 8];
#pragma unroll
      for (int nt = 0; nt < 4; ++nt) {
        const u16* wp = &wM1[(nt * 16 + c) * 136];
        f32x4 acc = __builtin_amdgcn_mfma_f32_16x16x32_bf16(a0, *(const short8*)(wp + q * 8), z, 0, 0, 0);
        acc = __builtin_amdgcn_mfma_f32_16x16x32_bf16(a1, *(const short8*)(wp + 32 + q * 8), acc, 0, 0, 0);
        acc = __builtin_amdgcn_mfma_f32_16x16x32_bf16(a2, *(const short8*)(wp + 64 + q * 8), acc, 0, 0, 0);
        acc = __builtin_amdgcn_mfma_f32_16x16x32_bf16(a3, *(const short8*)(wp + 96 + q * 8), acc, 0, 0, 0);
#pragma unroll
        for (int r = 0; r < 4; ++r) {
          int row = q * 4 + r, col = nt * 16 + c;
          ef1w[row][col] = f2b(silu_f(acc[r] + biasE[2][col]));
        }
      }
    }
    __builtin_amdgcn_wave_barrier();   // hAw reads done; msgfw may overlay
    // S4: msg MLP layer2 (K=64) -> msgfw (f32, +bias) overlaying hAw
    {
      short8 a0 = *(const short8*)&ef1w[c][q * 8];
      short8 a1 = *(const short8*)&ef1w[c][32 + q * 8];
      __builtin_amdgcn_wave_barrier();   // pin reads before overlay writes
#pragma unroll
      for (int nt = 0; nt < 4; ++nt) {
        short8 b0 = *(const short8*)&wM2[(nt * 16 + c) * 72 + q * 8];
        short8 b1v = *(const short8*)&wM2[(nt * 16 + c) * 72 + 32 + q * 8];
        f32x4 acc = __builtin_amdgcn_mfma_f32_16x16x32_bf16(a0, b0, z, 0, 0, 0);
        acc = __builtin_amdgcn_mfma_f32_16x16x32_bf16(a1, b1v, acc, 0, 0, 0);
#pragma unroll
        for (int r = 0; r < 4; ++r) {
          int row = q * 4 + r, col = nt * 16 + c;
          msgfw[row][col] = acc[r] + biasE[3][col];
        }
      }
    }
    __builtin_amdgcn_wave_barrier();

    // Issue next tile's geometry + h_node gathers; in flight across reduce,
    // waited at next tile's consume (register use). ptg/ntg NOT touched here
    // (still needed by this tile's reduce).
    __builtin_amdgcn_sched_barrier(0);
    if (tile + 1 < ETILES && base + 64 < Ev) {
      int gs2 = (int)(pkB & 0x1FFFFu);
      int tgc2 = (int)(pkB >> 17);
      if (lane < 16) {
        ps0 = loadF(node_pos, (long)gs2 * 3 + 0, pf);
        ps1 = loadF(node_pos, (long)gs2 * 3 + 1, pf);
        ps2 = loadF(node_pos, (long)gs2 * 3 + 2, pf);
        gp0 = loadF(grid_pos, (long)tgc2 * 3 + 0, gf);
        gp1 = loadF(grid_pos, (long)tgc2 * 3 + 1, gf);
        gp2 = loadF(grid_pos, (long)tgc2 * 3 + 2, gf);
        o0 = loadF(orient, (long)gs2 * 9 + 0, of);
        o1 = loadF(orient, (long)gs2 * 9 + 1, of);
        o2 = loadF(orient, (long)gs2 * 9 + 2, of);
        o3 = loadF(orient, (long)gs2 * 9 + 3, of);
        o4 = loadF(orient, (long)gs2 * 9 + 4, of);
        o5 = loadF(orient, (long)gs2 * 9 + 5, of);
        o6 = loadF(orient, (long)gs2 * 9 + 6, of);
        o7 = loadF(orient, (long)gs2 * 9 + 7, of);
        o8 = loadF(orient, (long)gs2 * 9 + 8, of);
      }
      unsigned int pks2 = (unsigned int)__shfl((int)pkB, lane >> 2);
      int ss2 = (int)(pks2 & 0x1FFFFu);
      const u16* hp2 = h_node + (long)ss2 * 64 + (lane & 3) * 16;
      hv0 = *(const short8*)hp2;
      hv1 = *(const short8*)(hp2 + 8);
    }
    __builtin_amdgcn_sched_barrier(0);

    // Run-reduction over the wave's 16 rows; col = lane. Targets via shfl
    // from lane r's mytg; boundary targets ptg/ntg from pkS (exact, so
    // atomic vs exclusive-store is positional & timing-independent).
    {
      int col = lane;
      int cur = __shfl(mytg, 0);
      float run = msgfw[0][col];
      bool lopen = (ptg == cur);
#pragma unroll
      for (int r2 = 1; r2 < 16; ++r2) {
        int tg = __shfl(mytg, r2);
        float v = msgfw[r2][col];
        if (tg == cur) {
          run += v;
        } else {
          if (cur >= 0) {
            if (lopen) unsafeAtomicAdd(&sums[(long)cur * 64 + col], run);
            else sums[(long)cur * 64 + col] = run;
          }
          cur = tg; run = v; lopen = false;
        }
      }
      bool ropen = (ntg == cur);
      if (cur >= 0) {
        if (lopen || ropen) unsafeAtomicAdd(&sums[(long)cur * 64 + col], run);
        else sums[(long)cur * 64 + col] = run;
      }
    }
    __builtin_amdgcn_wave_barrier();   // msgfw reads before next consume's hAw writes

    // boundary targets for next tile (reduce done; safe to overwrite)
    if (tile + 1 < ETILES && base + 64 < Ev) {
      long gPrev = base + 64 + m0 - 1;      // >= 63, always valid index
      long gNext = base + 64 + m0 + 16;
      ptg = (gPrev < Ev) ? (int)(pkS[gPrev] >> 17) : -2;
      ntg = (gNext < Ev) ? (int)(pkS[gNext] >> 17) : -2;
    }
    pkA = pkB; pkB = pkC; pkC = pkD;
  }
}

// ---------------------------------------------------------------------------
// Kernel 6: scatter-mean (sum of 8 count shards) + update MLP -> f32 out.
// One 64-row tile per block (512 blocks).
// ---------------------------------------------------------------------------
__global__ __launch_bounds__(256) void upd_mlp(
    const float* __restrict__ sums, const int* __restrict__ cnt8,
    const float* __restrict__ fw, float* __restrict__ out, int nrows)
{
  __shared__ float xs[64][68];
  __shared__ float w1s[64][68];
  __shared__ float w2s[64][68];
  __shared__ float b1s[64];
  __shared__ float b2s[64];
  const int t = threadIdx.x;
  const long rbase = (long)blockIdx.x * 64;
  for (int i = t; i < 4096; i += 256) {
    int k = i >> 6, cc = i & 63;
    w1s[k][cc] = fw[FW_UW1 + i];
    w2s[k][cc] = fw[FW_UW2 + i];
  }
  if (t < 64) { b1s[t] = fw[FW_UB1 + t]; b2s[t] = fw[FW_UB2 + t]; }
  {
    int row = t >> 2, ch = t & 3;
    long rg = rbase + row;
    if (rg < nrows) {
      int cn = 0;
#pragma unroll
      for (int cc = 0; cc < 8; ++cc) cn += cnt8[(size_t)cc * nrows + rg];
      float inv = 1.0f / fmaxf((float)cn, 1.0f);
      const float* p = sums + rg * 64 + ch * 16;
#pragma unroll
      for (int m = 0; m < 16; ++m) xs[row][ch * 16 + m] = p[m] * inv;
    } else {
#pragma unroll
      for (int m = 0; m < 16; ++m) xs[row][ch * 16 + m] = 0.f;
    }
  }
  __syncthreads();
  const int r0 = (t >> 4) * 4, c0 = (t & 15) * 4;
  float acc[4][4];
#pragma unroll
  for (int i = 0; i < 4; ++i)
#pragma unroll
    for (int j = 0; j < 4; ++j) acc[i][j] = b1s[c0 + j];
  for (int k = 0; k < 64; ++k) {
    float w0 = w1s[k][c0], w1v = w1s[k][c0 + 1], w2v = w1s[k][c0 + 2], w3v = w1s[k][c0 + 3];
#pragma unroll
    for (int i = 0; i < 4; ++i) {
      float av = xs[r0 + i][k];
      acc[i][0] = fmaf(av, w0, acc[i][0]);
      acc[i][1] = fmaf(av, w1v, acc[i][1]);
      acc[i][2] = fmaf(av, w2v, acc[i][2]);
      acc[i][3] = fmaf(av, w3v, acc[i][3]);
    }
  }
  __syncthreads();
#pragma unroll
  for (int i = 0; i < 4; ++i)
#pragma unroll
    for (int j = 0; j < 4; ++j) xs[r0 + i][c0 + j] = silu_f(acc[i][j]);
  __syncthreads();
  float acc2[4][4];
#pragma unroll
  for (int i = 0; i < 4; ++i)
#pragma unroll
    for (int j = 0; j < 4; ++j) acc2[i][j] = b2s[c0 + j];
  for (int k = 0; k < 64; ++k) {
    float w0 = w2s[k][c0], w1v = w2s[k][c0 + 1], w2v = w2s[k][c0 + 2], w3v = w2s[k][c0 + 3];
#pragma unroll
    for (int i = 0; i < 4; ++i) {
      float av = xs[r0 + i][k];
      acc2[i][0] = fmaf(av, w0, acc2[i][0]);
      acc2[i][1] = fmaf(av, w1v, acc2[i][1]);
      acc2[i][2] = fmaf(av, w2v, acc2[i][2]);
      acc2[i][3] = fmaf(av, w3v, acc2[i][3]);
    }
  }
#pragma unroll
  for (int i = 0; i < 4; ++i) {
    long rg = rbase + r0 + i;
    if (rg < nrows) {
#pragma unroll
      for (int j = 0; j < 4; ++j) out[rg * 64 + c0 + j] = acc2[i][j];
    }
  }
}

// ---------------------------------------------------------------------------
extern "C" void kernel_launch(void* const* d_in, const int* in_sizes, int n_in,
                              void* d_out, int out_size, void* d_ws, size_t ws_size,
                              hipStream_t stream) {
  const int N = in_sizes[1] / 3;
  const int G = in_sizes[2] / 3;
  const long E = (long)in_sizes[4] / 2;
  const int NB2 = (int)((8L * G + 1023) / 1024);   // <=256 for G<=32768
  const int nodeBlocks = (N + 63) / 64;

  char* ws = (char*)d_ws;
  float* sums = (float*)ws;
  size_t off = (size_t)G * 256;
  int* cnt8 = (int*)(ws + off);     off += (size_t)G * 32;   // 8 shards
  int* cursor8 = (int*)(ws + off);  off += (size_t)G * 32;
  int* bsum = (int*)(ws + off);     off += 1024;
  int* evp = (int*)(ws + off);      off += 256;
  int* flags = (int*)(ws + off);    off += 256;
  unsigned int* pkS = (unsigned int*)(ws + off); off += (size_t)E * 4;
  u16* h_node = (u16*)(ws + off);   off += (size_t)N * 128;
  u16* img = (u16*)(ws + off);      off += (size_t)IMG_TOTAL * 2;
  float* fw = (float*)(ws + off);

  // zero sums + cnt8 (ws poisoned 0xAA before every timed launch)
  hipMemsetAsync(ws, 0, (size_t)G * 288, stream);

  Ptrs a;
  const int map[20] = {0,1,2,3, 5,6,7,8, 9,10,11,12, 13,14,15,16, 17,18,19,20};
  for (int i = 0; i < 20; ++i) { a.p[i] = d_in[map[i]]; a.n[i] = in_sizes[map[i]]; }

  detect_k<<<20, 256, 0, stream>>>(a, flags);
  fused_hist_prep_node_k<<<HIST_BLOCKS + PREP_BLOCKS + nodeBlocks, 256, 0, stream>>>(
      a, (const int*)d_in[4], cnt8, flags, img, fw, h_node, N, G, E);
  scan_k<<<NB2, 256, 0, stream>>>(cnt8, cursor8, bsum, G);
  scat_k<<<1024, 256, 0, stream>>>((const int*)d_in[4], cursor8, bsum, pkS, evp, E, G, NB2);
  edge_kernel<<<(int)((E + ETILES * 64 - 1) / (ETILES * 64)), 256, 0, stream>>>(
      d_in[1], d_in[2], d_in[3], pkS, evp, h_node, img, fw, flags, sums, G);
  upd_mlp<<<(G + 63) / 64, 256, 0, stream>>>(sums, cnt8, fw, (float*)d_out, G);
}